// Round 1
// baseline (185.982 us; speedup 1.0000x reference)
//
#include <hip/hip_runtime.h>
#include <hip/hip_bf16.h>

#define B_N 8192
#define D_K 256
#define BM  32
#define BN  128
#define INVT 14.285714285714286f   // 1/0.07

typedef __bf16 bf16x8 __attribute__((ext_vector_type(8)));
typedef float  f32x4  __attribute__((ext_vector_type(4)));

#define AS1 __attribute__((address_space(1)))
#define AS3 __attribute__((address_space(3)))

__device__ __forceinline__ unsigned short f32_to_bf16_rne(float f) {
    unsigned int u = __float_as_uint(f);
    unsigned int r = (u + 0x7FFFu + ((u >> 16) & 1u)) >> 16;
    return (unsigned short)r;
}

__global__ void zero_out_kernel(float* out) { out[0] = 0.0f; }

// One block (256 threads) per row: L2-normalize, store bf16.
__global__ void norm_kernel(const float* __restrict__ emb,
                            unsigned short* __restrict__ en) {
    const int row = blockIdx.x;
    const int t   = threadIdx.x;
    float x  = emb[row * D_K + t];
    float ss = x * x;
    #pragma unroll
    for (int m = 32; m; m >>= 1) ss += __shfl_xor(ss, m, 64);
    __shared__ float wsum[4];
    if ((t & 63) == 0) wsum[t >> 6] = ss;
    __syncthreads();
    float tot = wsum[0] + wsum[1] + wsum[2] + wsum[3];
    float sc  = 1.0f / fmaxf(sqrtf(tot), 1e-12f);
    en[row * D_K + t] = f32_to_bf16_rne(x * sc);
}

// Grid 256 blocks, 4 waves each. Block owns BM=32 i-rows; streams all j in
// BN=128 tiles. sim never materialized: fused lse / pos_sum / pos_count.
__launch_bounds__(256, 1)
__global__ void loss_kernel(const unsigned short* __restrict__ en,
                            const int* __restrict__ labels,
                            float* __restrict__ out) {
    __shared__ unsigned short Bls[BN * D_K];   // 64 KB, chunk-XOR-swizzled
    __shared__ float comb[6][BM];

    const int t  = threadIdx.x;
    const int l  = t & 63;
    const int w  = t >> 6;
    const int wm = w & 1;          // which 16-row group
    const int wn = w >> 1;         // which 64-col half of the j-tile
    const int lr = l & 15;
    const int lg = l >> 4;
    const int ibase = blockIdx.x * BM;

    // ---- A fragments in registers: rows ibase + wm*16 + lr, all K ----
    bf16x8 a[8];
    {
        const unsigned short* ap =
            en + (size_t)(ibase + wm * 16 + lr) * D_K + lg * 8;
        #pragma unroll
        for (int ks = 0; ks < 8; ++ks)
            a[ks] = *reinterpret_cast<const bf16x8*>(ap + ks * 32);
    }

    const int i0 = ibase + wm * 16 + lg * 4;   // acc row base for this lane
    int li[4];
    #pragma unroll
    for (int r = 0; r < 4; ++r) li[r] = labels[i0 + r];

    float s[4]  = {0.f, 0.f, 0.f, 0.f};
    float ps[4] = {0.f, 0.f, 0.f, 0.f};
    float pc[4] = {0.f, 0.f, 0.f, 0.f};

    for (int it = 0; it < B_N / BN; ++it) {
        const int jbase = it * BN;

        __syncthreads();   // previous tile's reads done before overwrite
        // ---- stage B tile: linear LDS dest, inverse-swizzled global src ----
        #pragma unroll
        for (int rd = 0; rd < 16; ++rd) {
            int c    = rd * 256 + t;          // 16B-chunk index in LDS
            int row  = c >> 5;                // j-row within tile
            int m    = c & 31;                // chunk within row
            int srcm = m ^ (row & 7);         // involutive swizzle
            const unsigned short* g =
                en + (size_t)(jbase + row) * D_K + srcm * 8;
            __builtin_amdgcn_global_load_lds(
                (const AS1 void*)g,
                (AS3 void*)((unsigned short*)Bls + (size_t)c * 8),
                16, 0, 0);
        }
        __syncthreads();

        // ---- MFMA: 16 rows x 64 cols per wave over K=256 ----
        f32x4 acc[4] = {{0,0,0,0},{0,0,0,0},{0,0,0,0},{0,0,0,0}};
        #pragma unroll
        for (int ks = 0; ks < 8; ++ks) {
            #pragma unroll
            for (int nt = 0; nt < 4; ++nt) {
                int jl = wn * 64 + nt * 16 + lr;
                int mp = (lg + ks * 4) ^ (jl & 7);      // swizzled read
                const bf16x8 b = *reinterpret_cast<const bf16x8*>(
                    (const unsigned short*)Bls + (size_t)jl * D_K + mp * 8);
                acc[nt] = __builtin_amdgcn_mfma_f32_16x16x32_bf16(
                    a[ks], b, acc[nt], 0, 0, 0);
            }
        }

        // ---- fused softmax-denominator + positive-mask accumulation ----
        #pragma unroll
        for (int nt = 0; nt < 4; ++nt) {
            int jg = jbase + wn * 64 + nt * 16 + lr;
            int lj = labels[jg];
            #pragma unroll
            for (int r = 0; r < 4; ++r) {
                float dot = acc[nt][r];                 // raw cosine sim
                s[r] += __expf((dot - 1.0f) * INVT);    // static max = 1/T
                bool match = (lj == li[r]) & (jg != (i0 + r));
                ps[r] += match ? dot : 0.0f;
                pc[r] += match ? 1.0f : 0.0f;
            }
        }
    }

    // ---- reduce across the 16 column-lanes of each row ----
    #pragma unroll
    for (int r = 0; r < 4; ++r) {
        #pragma unroll
        for (int m = 1; m < 16; m <<= 1) {
            s[r]  += __shfl_xor(s[r],  m, 64);
            ps[r] += __shfl_xor(ps[r], m, 64);
            pc[r] += __shfl_xor(pc[r], m, 64);
        }
    }
    if (lr == 0) {
        #pragma unroll
        for (int r = 0; r < 4; ++r) {
            int rl = wm * 16 + lg * 4 + r;
            comb[wn * 3 + 0][rl] = s[r];
            comb[wn * 3 + 1][rl] = ps[r];
            comb[wn * 3 + 2][rl] = pc[r];
        }
    }
    __syncthreads();

    if (t < BM) {
        float st  = comb[0][t] + comb[3][t];
        float pst = (comb[1][t] + comb[4][t]) * INVT;
        float pct = comb[2][t] + comb[5][t];
        float lse = INVT + __logf(st);
        float loss = (pct > 0.0f) ? (lse - pst / pct) : 0.0f;
        #pragma unroll
        for (int m = 1; m < 32; m <<= 1) loss += __shfl_xor(loss, m, 64);
        if (t == 0) atomicAdd(out, loss * (1.0f / B_N));
    }
}

extern "C" void kernel_launch(void* const* d_in, const int* in_sizes, int n_in,
                              void* d_out, int out_size, void* d_ws, size_t ws_size,
                              hipStream_t stream) {
    const float* emb    = (const float*)d_in[0];
    const int*   labels = (const int*)d_in[1];
    float*       out    = (float*)d_out;
    unsigned short* en  = (unsigned short*)d_ws;   // 8192*256 bf16 = 4 MB

    hipLaunchKernelGGL(zero_out_kernel, dim3(1), dim3(1), 0, stream, out);
    hipLaunchKernelGGL(norm_kernel, dim3(B_N), dim3(D_K), 0, stream, emb, en);
    hipLaunchKernelGGL(loss_kernel, dim3(B_N / BM), dim3(256), 0, stream,
                       en, labels, out);
}

// Round 3
// 131.112 us; speedup vs baseline: 1.4185x; 1.4185x over previous
//
#include <hip/hip_runtime.h>
#include <hip/hip_bf16.h>

#define B_N 8192
#define D_K 256
#define BM  32
#define BN  128
#define JSPLIT 2
#define JSPAN (B_N / JSPLIT)
#define NTILE (JSPAN / BN)
#define INVT 14.285714285714286f   // 1/0.07

typedef __bf16 bf16x8 __attribute__((ext_vector_type(8)));
typedef float  f32x16 __attribute__((ext_vector_type(16)));

#define AS1 __attribute__((address_space(1)))
#define AS3 __attribute__((address_space(3)))

__device__ __forceinline__ unsigned short f32_to_bf16_rne(float f) {
    unsigned int u = __float_as_uint(f);
    unsigned int r = (u + 0x7FFFu + ((u >> 16) & 1u)) >> 16;
    return (unsigned short)r;
}

__global__ void zero_misc(float* out, int* hist) {
    if (threadIdx.x < 1024) hist[threadIdx.x] = 0;
    if (threadIdx.x == 0) out[0] = 0.0f;
}

// One block per row: L2-normalize to bf16; build label histogram.
__global__ void norm_kernel(const float* __restrict__ emb,
                            unsigned short* __restrict__ en,
                            const int* __restrict__ labels,
                            int* __restrict__ hist) {
    const int row = blockIdx.x;
    const int t   = threadIdx.x;
    float x  = emb[row * D_K + t];
    float ss = x * x;
    #pragma unroll
    for (int m = 32; m; m >>= 1) ss += __shfl_xor(ss, m, 64);
    __shared__ float wsum[4];
    if ((t & 63) == 0) wsum[t >> 6] = ss;
    __syncthreads();
    float tot = wsum[0] + wsum[1] + wsum[2] + wsum[3];
    float sc  = 1.0f / fmaxf(sqrtf(tot), 1e-12f);
    en[row * D_K + t] = f32_to_bf16_rne(x * sc);
    if (t == 0) atomicAdd(&hist[labels[row]], 1);
}

// Swapped-operand scheme: D[m=j][n=i]. Each wave owns one 32-row j-group of
// the 128-row LDS tile; i-side (32 rows) resident in registers. s/ps collapse
// to one register per lane. Grid = 256 i-tiles x JSPLIT, 2 blocks/CU.
__launch_bounds__(256, 2)
__global__ void loss_kernel(const unsigned short* __restrict__ en,
                            const int* __restrict__ labels,
                            float* __restrict__ s_part,
                            float* __restrict__ ps_part) {
    __shared__ unsigned short Bls[BN * D_K];   // 64 KB, chunk-XOR-swizzled
    __shared__ int   Lls[BN];
    __shared__ float comb[2][4][BM];

    const int t  = threadIdx.x;
    const int l  = t & 63;
    const int w  = t >> 6;
    const int ir = l & 31;
    const int h  = l >> 5;

    // XCD-aware swizzle: same-jsplit, consecutive-itile blocks share an XCD L2
    const int b   = blockIdx.x;
    const int swz = (b & 7) * (gridDim.x >> 3) + (b >> 3);
    const int jsplit = swz >> 8;           // swz / 256
    const int itile  = swz & 255;
    const int ibase  = itile * BM;
    const int j0base = jsplit * JSPAN;

    // ---- resident i-side fragments (B operand): 16 ks-slices, 64 VGPR ----
    bf16x8 bi[16];
    {
        const unsigned short* ap = en + (size_t)(ibase + ir) * D_K + h * 8;
        #pragma unroll
        for (int ks = 0; ks < 16; ++ks)
            bi[ks] = *reinterpret_cast<const bf16x8*>(ap + ks * 16);
    }
    const int i_glob = ibase + ir;
    const int li = labels[i_glob];

    float s_acc = 0.0f, ps_acc = 0.0f;

    for (int it = 0; it < NTILE; ++it) {
        const int j0g = j0base + it * BN;

        __syncthreads();   // previous tile's reads done before overwrite
        #pragma unroll
        for (int rd = 0; rd < 16; ++rd) {
            int c    = rd * 256 + t;       // 16B-chunk index in LDS
            int row  = c >> 5;
            int m16  = c & 31;
            int srcm = m16 ^ (row & 7);    // involutive swizzle (src side)
            const unsigned short* g =
                en + (size_t)(j0g + row) * D_K + srcm * 8;
            __builtin_amdgcn_global_load_lds(
                (const AS1 void*)g,
                (AS3 void*)((unsigned short*)Bls + (size_t)c * 8), 16, 0, 0);
        }
        if (t < BN) Lls[t] = labels[j0g + t];
        __syncthreads();

        // ---- 16-step MFMA chain: j-group rows (A) x resident i (B) ----
        f32x16 acc;
        #pragma unroll
        for (int q = 0; q < 16; ++q) acc[q] = 0.0f;
        const int x = ir & 7;
        const char* arow = (const char*)Bls + (size_t)(w * 32 + ir) * 512;
        #pragma unroll
        for (int ks = 0; ks < 16; ++ks) {
            int chunk = ((ks << 1) | h) ^ x;   // swizzled 16B-chunk
            const bf16x8 af =
                *reinterpret_cast<const bf16x8*>(arow + (chunk << 4));
            acc = __builtin_amdgcn_mfma_f32_32x32x16_bf16(af, bi[ks], acc,
                                                          0, 0, 0);
        }

        // ---- fused softmax-denom + positive-sum (lane-local j-reduction) ----
        const bool dtile = (j0g == (ibase & ~(BN - 1)));
        if (dtile) {
            #pragma unroll
            for (int r = 0; r < 16; ++r) {
                int jl = w * 32 + (r & 3) + ((r >> 2) << 3) + (h << 2);
                int lj = Lls[jl];
                float dot = acc[r];
                s_acc += __expf(fmaf(dot, INVT, -INVT));
                bool mm = (lj == li) & ((j0g + jl) != i_glob);
                ps_acc += mm ? dot : 0.0f;
            }
        } else {
            #pragma unroll
            for (int r = 0; r < 16; ++r) {
                int jl = w * 32 + (r & 3) + ((r >> 2) << 3) + (h << 2);
                int lj = Lls[jl];
                float dot = acc[r];
                s_acc += __expf(fmaf(dot, INVT, -INVT));
                ps_acc += (lj == li) ? dot : 0.0f;
            }
        }
    }

    // ---- combine: halves, then the 4 waves; write per-split partials ----
    s_acc  += __shfl_xor(s_acc, 32, 64);
    ps_acc += __shfl_xor(ps_acc, 32, 64);
    if (h == 0) { comb[0][w][ir] = s_acc; comb[1][w][ir] = ps_acc; }
    __syncthreads();
    if (t < BM) {
        float st  = comb[0][0][t] + comb[0][1][t] + comb[0][2][t] + comb[0][3][t];
        float pst = comb[1][0][t] + comb[1][1][t] + comb[1][2][t] + comb[1][3][t];
        s_part[jsplit * B_N + ibase + t]  = st;
        ps_part[jsplit * B_N + ibase + t] = pst;
    }
}

__global__ void final_kernel(const float* __restrict__ s_part,
                             const float* __restrict__ ps_part,
                             const int* __restrict__ labels,
                             const int* __restrict__ hist,
                             float* __restrict__ out) {
    int i = blockIdx.x * 256 + threadIdx.x;
    float s  = s_part[i] + s_part[B_N + i];
    float ps = ps_part[i] + ps_part[B_N + i];
    int pc = hist[labels[i]] - 1;
    float lse = INVT + __logf(s);
    float loss = (pc > 0) ? (lse - ps * INVT / (float)pc) : 0.0f;
    #pragma unroll
    for (int m = 1; m < 64; m <<= 1) loss += __shfl_xor(loss, m, 64);
    __shared__ float ws4[4];
    if ((threadIdx.x & 63) == 0) ws4[threadIdx.x >> 6] = loss;
    __syncthreads();
    if (threadIdx.x == 0)
        atomicAdd(out, (ws4[0] + ws4[1] + ws4[2] + ws4[3]) * (1.0f / B_N));
}

extern "C" void kernel_launch(void* const* d_in, const int* in_sizes, int n_in,
                              void* d_out, int out_size, void* d_ws, size_t ws_size,
                              hipStream_t stream) {
    const float* emb    = (const float*)d_in[0];
    const int*   labels = (const int*)d_in[1];
    float*       out    = (float*)d_out;

    unsigned short* en  = (unsigned short*)d_ws;              // 4 MB
    float* s_part  = (float*)((char*)d_ws + (size_t)B_N * D_K * 2);
    float* ps_part = s_part + JSPLIT * B_N;
    int*   hist    = (int*)(ps_part + JSPLIT * B_N);          // 1024 ints

    hipLaunchKernelGGL(zero_misc, dim3(1), dim3(1024), 0, stream, out, hist);
    hipLaunchKernelGGL(norm_kernel, dim3(B_N), dim3(D_K), 0, stream,
                       emb, en, labels, hist);
    hipLaunchKernelGGL(loss_kernel, dim3(256 * JSPLIT), dim3(256), 0, stream,
                       en, labels, s_part, ps_part);
    hipLaunchKernelGGL(final_kernel, dim3(B_N / 256), dim3(256), 0, stream,
                       s_part, ps_part, labels, hist, out);
}